// Round 5
// baseline (114.519 us; speedup 1.0000x reference)
//
#include <hip/hip_runtime.h>
#include <hip/hip_bf16.h>

// ViT embed: patchify + linear + cls + posemb + LayerNorm, fused.
// images [128,3,224,224] f32 -> out [128,197,768] f32.
// M = 128*196 = 25088 patch-rows, K = 768, N = 768.
// v5: B direct L2->reg double-buffer (no LDS, no DMA, imm-offset addressing),
// A via tiny swizzled LDS dbuf (4KB/step) fenced by raw s_barrier+lgkmcnt only
// (B/image loads never drained). Full 24x unroll -> compiler-exact vmcnt.
// __launch_bounds__(512,2) so the dbuf actually gets registers (prev rounds
// were silently capped at 128 VGPR).

#define IMG_B 128
#define IMG_C 3
#define IMG_HW 224
#define DTOK 768
#define NTOK 197
#define MROWS 25088

typedef __attribute__((ext_vector_type(4))) float f32x4;
typedef __attribute__((ext_vector_type(8))) short bf16x8;
typedef __attribute__((ext_vector_type(4))) short bf16x4;

__device__ __forceinline__ unsigned short f2b(float f) {
  union { float f; unsigned u; } v; v.f = f;
  unsigned u = v.u;
  return (unsigned short)((u + 0x7fffu + ((u >> 16) & 1u)) >> 16);
}

// ---------------- setup kernels ----------------

__global__ void conv_w(const float* __restrict__ W, unsigned short* __restrict__ Wb) {
  int i = blockIdx.x * 256 + threadIdx.x;
  if (i < DTOK * DTOK) Wb[i] = f2b(W[i]);
}

__global__ void make_bpos(const float* __restrict__ bias, const float* __restrict__ cls,
                          float* __restrict__ bpos) {
  int i = blockIdx.x * 256 + threadIdx.x;
  if (i >= NTOK * DTOK) return;
  int t = i / DTOK, d = i - (i / DTOK) * DTOK;
  float expo = (float)(d & ~1) * (1.0f / (float)DTOK);
  float angle = (float)t * exp2f(-expo * 13.287712379549449f);
  float pv = (d & 1) ? cosf(angle) : sinf(angle);
  bpos[i] = pv + ((t == 0) ? cls[d] : bias[d]);
}

__global__ __launch_bounds__(256) void cls_kernel(const float* __restrict__ bpos,
                                                  const float* __restrict__ gamma,
                                                  const float* __restrict__ beta,
                                                  float* __restrict__ out) {
  __shared__ float sred[8];
  const int tid = threadIdx.x;
  float v0 = bpos[tid], v1 = bpos[tid + 256], v2 = bpos[tid + 512];
  float s1 = v0 + v1 + v2;
  float s2 = v0 * v0 + v1 * v1 + v2 * v2;
  #pragma unroll
  for (int off = 32; off >= 1; off >>= 1) {
    s1 += __shfl_xor(s1, off, 64);
    s2 += __shfl_xor(s2, off, 64);
  }
  if ((tid & 63) == 0) { sred[(tid >> 6) * 2] = s1; sred[(tid >> 6) * 2 + 1] = s2; }
  __syncthreads();
  float S1 = sred[0] + sred[2] + sred[4] + sred[6];
  float S2 = sred[1] + sred[3] + sred[5] + sred[7];
  float mean = S1 * (1.0f / 768.0f);
  float rstd = rsqrtf(S2 * (1.0f / 768.0f) - mean * mean + 1e-5f);
  float o0 = (v0 - mean) * rstd * gamma[tid] + beta[tid];
  float o1 = (v1 - mean) * rstd * gamma[tid + 256] + beta[tid + 256];
  float o2 = (v2 - mean) * rstd * gamma[tid + 512] + beta[tid + 512];
  for (int b = 0; b < IMG_B; ++b) {
    float* op = out + (size_t)b * NTOK * DTOK;
    op[tid] = o0; op[tid + 256] = o1; op[tid + 512] = o2;
  }
}

// ---------------- main fused kernel ----------------
// 512 thr / 8 waves (N-slices of 96 cols). BM=64, BK=32, 24 K-steps.
// A LDS: rows of 32 bf16 = 4 16B-slots; content quad q of row r stored at
// slot q ^ ((r>>1)&3)  -> conflict-free ds_read_b128 (verified 0 in R4).

__global__ __launch_bounds__(512, 2) void vit_main(
    const float* __restrict__ images, const unsigned short* __restrict__ Wb,
    const float* __restrict__ bpos, const float* __restrict__ gamma,
    const float* __restrict__ beta, float* __restrict__ out) {
  __shared__ __align__(16) unsigned short Al[2][2048];  // 2 x 4KB (64 rows x 32 bf16)
  __shared__ float red[8][64][2];
  __shared__ float rowstat[64][2];

  const int tid = threadIdx.x;
  const int wid = tid >> 6;
  const int lane = tid & 63;
  const int l15 = lane & 15;
  const int g = lane >> 4;
  const int blk = blockIdx.x;
  const int cbase = wid * 96;

  // ---- A staging role: thread -> (srow 0..63, kq 0..7) ----
  const int srow = tid >> 3;
  const int kq = tid & 7;
  const int sm = blk * 64 + srow;
  const int sb = sm / 196;
  const int sp = sm - sb * 196;
  const int spy = sp / 14, spx = sp - (sp / 14) * 14;
  const int bq = kq >> 2;
  // fold (kq&3)*4 pixel offset and bq*224 row-parity offset into the base;
  // per-step offset is then the COMPILE-TIME constant (t>>3)*50176 + ((2t)&15)*224.
  const float* abase = images + (size_t)sb * (IMG_C * IMG_HW * IMG_HW) +
                       (spy * 16) * IMG_HW + spx * 16 + (kq & 3) * 4 + bq * IMG_HW;
  // A LDS write index (ushorts): slot = srow*4 + ((kq>>1) ^ ((srow>>1)&3)), half = kq&1
  const int aw_idx = (srow * 4 + ((kq >> 1) ^ ((srow >> 1) & 3))) * 8 + (kq & 1) * 4;
  // A frag read (swizzled, zero-conflict): + mf*512
  const int sA = g ^ ((l15 >> 1) & 3);
  const int ard = l15 * 32 + sA * 8;

  // ---- B: per-lane base per nf; step k adds k*32 ushorts = k*64 B (imm) ----
  const unsigned short* bbase[6];
  #pragma unroll
  for (int nf = 0; nf < 6; ++nf)
    bbase[nf] = Wb + (size_t)(cbase + nf * 16 + l15) * DTOK + g * 8;

  f32x4 acc[4][6];
  #pragma unroll
  for (int mf = 0; mf < 4; ++mf)
    #pragma unroll
    for (int nf = 0; nf < 6; ++nf)
      acc[mf][nf] = (f32x4)(0.0f);

#define AOFF(t) (((t) >> 3) * 50176 + (((2 * (t)) & 15)) * 224)

  float4 imgreg[2];   // img(k+2) issued at top of step k into imgreg[k&1]
  bf16x8 bfr[2][6];   // B(k) lives in bfr[k&1]

  // ---- prologue: stage A(0); load img(1); load B(0),B(1) ----
  {
    const float4 a0 = *(const float4*)(abase + AOFF(0));
    imgreg[1] = *(const float4*)(abase + AOFF(1));
    #pragma unroll
    for (int nf = 0; nf < 6; ++nf) {
      bfr[0][nf] = *(const bf16x8*)(bbase[nf]);
      bfr[1][nf] = *(const bf16x8*)(bbase[nf] + 32);
    }
    union { __hip_bfloat162 h2[2]; bf16x4 v4; } u;
    u.h2[0] = __float22bfloat162_rn(make_float2(a0.x, a0.y));
    u.h2[1] = __float22bfloat162_rn(make_float2(a0.z, a0.w));
    *(bf16x4*)&Al[0][aw_idx] = u.v4;
    asm volatile("s_waitcnt lgkmcnt(0)" ::: "memory");
    __builtin_amdgcn_s_barrier();
    __builtin_amdgcn_sched_barrier(0);
  }

  // ---- K-loop, fully unrolled; raw barrier never drains vmcnt ----
  #pragma unroll
  for (int k = 0; k < 24; ++k) {
    // issue img(k+2) (consumed at end of step k+1)
    if (k + 2 < 24)
      imgreg[k & 1] = *(const float4*)(abase + AOFF(k + 2));

    bf16x8 afr[4];
    #pragma unroll
    for (int mf = 0; mf < 4; ++mf)
      afr[mf] = *(const bf16x8*)&Al[k & 1][ard + mf * 512];

    #pragma unroll
    for (int nf = 0; nf < 6; ++nf)
      #pragma unroll
      for (int mf = 0; mf < 4; ++mf)
        acc[mf][nf] = __builtin_amdgcn_mfma_f32_16x16x32_bf16(
            afr[mf], bfr[k & 1][nf], acc[mf][nf], 0, 0, 0);

    // refill bfr[k&1] with B(k+2) AFTER its last use (WAR-clean)
    if (k + 2 < 24) {
      #pragma unroll
      for (int nf = 0; nf < 6; ++nf)
        bfr[k & 1][nf] = *(const bf16x8*)(bbase[nf] + (k + 2) * 32);
    }

    // cvt img(k+1) (loaded at step k-1) and stage A(k+1)
    if (k + 1 < 24) {
      const float4 av = imgreg[(k + 1) & 1];
      union { __hip_bfloat162 h2[2]; bf16x4 v4; } u;
      u.h2[0] = __float22bfloat162_rn(make_float2(av.x, av.y));
      u.h2[1] = __float22bfloat162_rn(make_float2(av.z, av.w));
      *(bf16x4*)&Al[(k + 1) & 1][aw_idx] = u.v4;
    }
    asm volatile("s_waitcnt lgkmcnt(0)" ::: "memory");
    __builtin_amdgcn_s_barrier();
    __builtin_amdgcn_sched_barrier(0);
  }
#undef AOFF

  // ---- epilogue: +bias+pos, row LN over full 768 (all in-block) ----
  float s1[16], s2[16];
  #pragma unroll
  for (int mf = 0; mf < 4; ++mf) {
    #pragma unroll
    for (int r = 0; r < 4; ++r) {
      const int rl = mf * 16 + g * 4 + r;
      const int m = blk * 64 + rl;
      const int trow = 1 + (m % 196);
      const float* bp = bpos + (size_t)trow * DTOK + cbase + l15;
      float a1 = 0.f, a2 = 0.f;
      #pragma unroll
      for (int nf = 0; nf < 6; ++nf) {
        float val = acc[mf][nf][r] + bp[nf * 16];
        acc[mf][nf][r] = val;
        a1 += val; a2 += val * val;
      }
      s1[mf * 4 + r] = a1; s2[mf * 4 + r] = a2;
    }
  }
  #pragma unroll
  for (int off = 8; off >= 1; off >>= 1) {
    #pragma unroll
    for (int i = 0; i < 16; ++i) {
      s1[i] += __shfl_xor(s1[i], off, 64);
      s2[i] += __shfl_xor(s2[i], off, 64);
    }
  }
  if (l15 == 0) {
    #pragma unroll
    for (int mf = 0; mf < 4; ++mf)
      #pragma unroll
      for (int r = 0; r < 4; ++r) {
        const int rl = mf * 16 + g * 4 + r;
        red[wid][rl][0] = s1[mf * 4 + r];
        red[wid][rl][1] = s2[mf * 4 + r];
      }
  }
  __syncthreads();
  if (tid < 64) {
    float S1 = 0.f, S2 = 0.f;
    #pragma unroll
    for (int w = 0; w < 8; ++w) { S1 += red[w][tid][0]; S2 += red[w][tid][1]; }
    float mean = S1 * (1.0f / 768.0f);
    float var = S2 * (1.0f / 768.0f) - mean * mean;
    rowstat[tid][0] = mean;
    rowstat[tid][1] = rsqrtf(var + 1e-5f);
  }
  __syncthreads();

  float gm[6], bt[6];
  #pragma unroll
  for (int nf = 0; nf < 6; ++nf) {
    gm[nf] = gamma[cbase + nf * 16 + l15];
    bt[nf] = beta[cbase + nf * 16 + l15];
  }
  #pragma unroll
  for (int mf = 0; mf < 4; ++mf) {
    #pragma unroll
    for (int r = 0; r < 4; ++r) {
      const int rl = mf * 16 + g * 4 + r;
      const int m = blk * 64 + rl;
      const int bb = m / 196;
      const int orow = bb * 197 + 1 + (m - bb * 196);
      const float mean = rowstat[rl][0], rstd = rowstat[rl][1];
      float* op = out + (size_t)orow * DTOK + cbase + l15;
      #pragma unroll
      for (int nf = 0; nf < 6; ++nf)
        op[nf * 16] = (acc[mf][nf][r] - mean) * rstd * gm[nf] + bt[nf];
    }
  }
}

extern "C" void kernel_launch(void* const* d_in, const int* in_sizes, int n_in,
                              void* d_out, int out_size, void* d_ws, size_t ws_size,
                              hipStream_t stream) {
  const float* images = (const float*)d_in[0];
  const float* W      = (const float*)d_in[1];
  const float* bias   = (const float*)d_in[2];
  const float* cls    = (const float*)d_in[3];
  const float* gamma  = (const float*)d_in[4];
  const float* beta   = (const float*)d_in[5];
  float* out = (float*)d_out;

  unsigned short* Wb = (unsigned short*)d_ws;                       // 768*768*2 B
  float* bpos = (float*)((char*)d_ws + (size_t)DTOK * DTOK * 2);    // 197*768*4 B

  conv_w<<<(DTOK * DTOK + 255) / 256, 256, 0, stream>>>(W, Wb);
  make_bpos<<<(NTOK * DTOK + 255) / 256, 256, 0, stream>>>(bias, cls, bpos);
  cls_kernel<<<1, 256, 0, stream>>>(bpos, gamma, beta, out);
  vit_main<<<MROWS / 64, 512, 0, stream>>>(images, Wb, bpos, gamma, beta, out);
}

// Round 7
// 113.443 us; speedup vs baseline: 1.0095x; 1.0095x over previous
//
#include <hip/hip_runtime.h>
#include <hip/hip_bf16.h>

// ViT embed: patchify + linear + cls + posemb + LayerNorm, fused.
// images [128,3,224,224] f32 -> out [128,197,768] f32.
// M = 128*196 = 25088 patch-rows, K = 768, N = 768.
// v7: unlock the register budget. R1-R5 all ran at VGPR_Count=128 -> only
// 1-2 loads in flight -> ~14 loads/K-step serialized at L2/L3 latency.
// amdgpu_waves_per_eu(2,2) caps occupancy at 2 waves/SIMD -> 256-reg budget,
// so the declared pipelines (B triple-buffer, img depth-3) get real registers.
// No sched_barrier(0) (it forced spills), no PIN (wrong: pinning = waiting).
// B(k+2) refill issued BEFORE the MFMA block (triple buffer -> no WAR).

#define IMG_B 128
#define IMG_C 3
#define IMG_HW 224
#define DTOK 768
#define NTOK 197
#define MROWS 25088

typedef __attribute__((ext_vector_type(4))) float f32x4;
typedef __attribute__((ext_vector_type(8))) short bf16x8;
typedef __attribute__((ext_vector_type(4))) short bf16x4;

__device__ __forceinline__ unsigned short f2b(float f) {
  union { float f; unsigned u; } v; v.f = f;
  unsigned u = v.u;
  return (unsigned short)((u + 0x7fffu + ((u >> 16) & 1u)) >> 16);
}

// ---------------- setup kernels ----------------

__global__ void conv_w(const float* __restrict__ W, unsigned short* __restrict__ Wb) {
  int i = blockIdx.x * 256 + threadIdx.x;
  if (i < DTOK * DTOK) Wb[i] = f2b(W[i]);
}

__global__ void make_bpos(const float* __restrict__ bias, const float* __restrict__ cls,
                          float* __restrict__ bpos) {
  int i = blockIdx.x * 256 + threadIdx.x;
  if (i >= NTOK * DTOK) return;
  int t = i / DTOK, d = i - (i / DTOK) * DTOK;
  float expo = (float)(d & ~1) * (1.0f / (float)DTOK);
  float angle = (float)t * exp2f(-expo * 13.287712379549449f);
  float pv = (d & 1) ? cosf(angle) : sinf(angle);
  bpos[i] = pv + ((t == 0) ? cls[d] : bias[d]);
}

__global__ __launch_bounds__(256) void cls_kernel(const float* __restrict__ bpos,
                                                  const float* __restrict__ gamma,
                                                  const float* __restrict__ beta,
                                                  float* __restrict__ out) {
  __shared__ float sred[8];
  const int tid = threadIdx.x;
  float v0 = bpos[tid], v1 = bpos[tid + 256], v2 = bpos[tid + 512];
  float s1 = v0 + v1 + v2;
  float s2 = v0 * v0 + v1 * v1 + v2 * v2;
  #pragma unroll
  for (int off = 32; off >= 1; off >>= 1) {
    s1 += __shfl_xor(s1, off, 64);
    s2 += __shfl_xor(s2, off, 64);
  }
  if ((tid & 63) == 0) { sred[(tid >> 6) * 2] = s1; sred[(tid >> 6) * 2 + 1] = s2; }
  __syncthreads();
  float S1 = sred[0] + sred[2] + sred[4] + sred[6];
  float S2 = sred[1] + sred[3] + sred[5] + sred[7];
  float mean = S1 * (1.0f / 768.0f);
  float rstd = rsqrtf(S2 * (1.0f / 768.0f) - mean * mean + 1e-5f);
  float o0 = (v0 - mean) * rstd * gamma[tid] + beta[tid];
  float o1 = (v1 - mean) * rstd * gamma[tid + 256] + beta[tid + 256];
  float o2 = (v2 - mean) * rstd * gamma[tid + 512] + beta[tid + 512];
  for (int b = 0; b < IMG_B; ++b) {
    float* op = out + (size_t)b * NTOK * DTOK;
    op[tid] = o0; op[tid + 256] = o1; op[tid + 512] = o2;
  }
}

// ---------------- main fused kernel ----------------
// 512 thr / 8 waves (N-slices of 96 cols). BM=64, BK=32, 24 K-steps.
// A LDS: rows of 32 bf16 = 4 16B-slots; content quad q of row r stored at
// slot q ^ ((r>>1)&3)  -> conflict-free ds_read_b128 (verified 0 since R4).

__global__ __launch_bounds__(512)
__attribute__((amdgpu_waves_per_eu(2, 2))) void vit_main(
    const float* __restrict__ images, const unsigned short* __restrict__ Wb,
    const float* __restrict__ bpos, const float* __restrict__ gamma,
    const float* __restrict__ beta, float* __restrict__ out) {
  __shared__ __align__(16) unsigned short Al[2][2048];  // 2 x 4KB (64 rows x 32 bf16)
  __shared__ float red[8][64][2];
  __shared__ float rowstat[64][2];

  const int tid = threadIdx.x;
  const int wid = tid >> 6;
  const int lane = tid & 63;
  const int l15 = lane & 15;
  const int g = lane >> 4;
  const int blk = blockIdx.x;
  const int cbase = wid * 96;

  // ---- A staging role: thread -> (srow 0..63, kq 0..7) ----
  const int srow = tid >> 3;
  const int kq = tid & 7;
  const int sm = blk * 64 + srow;
  const int sb = sm / 196;
  const int sp = sm - sb * 196;
  const int spy = sp / 14, spx = sp - (sp / 14) * 14;
  const int bq = kq >> 2;
  // per-step offset from abase is the compile-time constant AOFF(t).
  const float* abase = images + (size_t)sb * (IMG_C * IMG_HW * IMG_HW) +
                       (spy * 16) * IMG_HW + spx * 16 + (kq & 3) * 4 + bq * IMG_HW;
  // A LDS write index (ushorts): slot = srow*4 + ((kq>>1) ^ ((srow>>1)&3)), half = kq&1
  const int aw_idx = (srow * 4 + ((kq >> 1) ^ ((srow >> 1) & 3))) * 8 + (kq & 1) * 4;
  // A frag read (swizzled, zero-conflict): + mf*512
  const int sA = g ^ ((l15 >> 1) & 3);
  const int ard = l15 * 32 + sA * 8;

  // ---- B: per-lane base per nf; step k adds k*32 ushorts = k*64 B (imm) ----
  const unsigned short* bbase[6];
  #pragma unroll
  for (int nf = 0; nf < 6; ++nf)
    bbase[nf] = Wb + (size_t)(cbase + nf * 16 + l15) * DTOK + g * 8;

  f32x4 acc[4][6];
  #pragma unroll
  for (int mf = 0; mf < 4; ++mf)
    #pragma unroll
    for (int nf = 0; nf < 6; ++nf)
      acc[mf][nf] = (f32x4)(0.0f);

#define AOFF(t) (((t) >> 3) * 50176 + (((2 * (t)) & 15)) * 224)

  float4 imgreg[3];   // img(t) lives in imgreg[t % 3]; depth-3 pipeline
  bf16x8 bfr[3][6];   // B(k)  lives in bfr[k % 3];  depth-3 (refill pre-MFMA)

  // ---- prologue: img(0) direct + stage A(0); issue img(1),img(2), B(0),B(1) ----
  {
    const float4 a0 = *(const float4*)(abase + AOFF(0));
    imgreg[1] = *(const float4*)(abase + AOFF(1));
    imgreg[2] = *(const float4*)(abase + AOFF(2));
    #pragma unroll
    for (int nf = 0; nf < 6; ++nf) {
      bfr[0][nf] = *(const bf16x8*)(bbase[nf]);
      bfr[1][nf] = *(const bf16x8*)(bbase[nf] + 32);
    }
    union { __hip_bfloat162 h2[2]; bf16x4 v4; } u;
    u.h2[0] = __float22bfloat162_rn(make_float2(a0.x, a0.y));
    u.h2[1] = __float22bfloat162_rn(make_float2(a0.z, a0.w));
    *(bf16x4*)&Al[0][aw_idx] = u.v4;
    asm volatile("s_waitcnt lgkmcnt(0)" ::: "memory");
    __builtin_amdgcn_s_barrier();
  }

  // ---- K-loop, fully unrolled; barrier waits LDS only (vmcnt stays live) ----
  #pragma unroll
  for (int k = 0; k < 24; ++k) {
    // issue img(k+3): consumed (cvt) at step k+2
    if (k + 3 < 24)
      imgreg[(k + 3) % 3] = *(const float4*)(abase + AOFF(k + 3));

    // issue B(k+2) BEFORE the MFMAs (triple buffer -> no WAR with bfr[k%3])
    if (k + 2 < 24) {
      #pragma unroll
      for (int nf = 0; nf < 6; ++nf)
        bfr[(k + 2) % 3][nf] = *(const bf16x8*)(bbase[nf] + (k + 2) * 32);
    }

    bf16x8 afr[4];
    #pragma unroll
    for (int mf = 0; mf < 4; ++mf)
      afr[mf] = *(const bf16x8*)&Al[k & 1][ard + mf * 512];

    #pragma unroll
    for (int nf = 0; nf < 6; ++nf)
      #pragma unroll
      for (int mf = 0; mf < 4; ++mf)
        acc[mf][nf] = __builtin_amdgcn_mfma_f32_16x16x32_bf16(
            afr[mf], bfr[k % 3][nf], acc[mf][nf], 0, 0, 0);

    // cvt img(k+1) (issued at step k-2 -> ~2 steps of flight) and stage A(k+1)
    if (k + 1 < 24) {
      const float4 av = imgreg[(k + 1) % 3];
      union { __hip_bfloat162 h2[2]; bf16x4 v4; } u;
      u.h2[0] = __float22bfloat162_rn(make_float2(av.x, av.y));
      u.h2[1] = __float22bfloat162_rn(make_float2(av.z, av.w));
      *(bf16x4*)&Al[(k + 1) & 1][aw_idx] = u.v4;
    }
    asm volatile("s_waitcnt lgkmcnt(0)" ::: "memory");
    __builtin_amdgcn_s_barrier();
  }
#undef AOFF

  // ---- epilogue: +bias+pos, row LN over full 768 (all in-block) ----
  float s1[16], s2[16];
  #pragma unroll
  for (int mf = 0; mf < 4; ++mf) {
    #pragma unroll
    for (int r = 0; r < 4; ++r) {
      const int rl = mf * 16 + g * 4 + r;
      const int m = blk * 64 + rl;
      const int trow = 1 + (m % 196);
      const float* bp = bpos + (size_t)trow * DTOK + cbase + l15;
      float a1 = 0.f, a2 = 0.f;
      #pragma unroll
      for (int nf = 0; nf < 6; ++nf) {
        float val = acc[mf][nf][r] + bp[nf * 16];
        acc[mf][nf][r] = val;
        a1 += val; a2 += val * val;
      }
      s1[mf * 4 + r] = a1; s2[mf * 4 + r] = a2;
    }
  }
  #pragma unroll
  for (int off = 8; off >= 1; off >>= 1) {
    #pragma unroll
    for (int i = 0; i < 16; ++i) {
      s1[i] += __shfl_xor(s1[i], off, 64);
      s2[i] += __shfl_xor(s2[i], off, 64);
    }
  }
  if (l15 == 0) {
    #pragma unroll
    for (int mf = 0; mf < 4; ++mf)
      #pragma unroll
      for (int r = 0; r < 4; ++r) {
        const int rl = mf * 16 + g * 4 + r;
        red[wid][rl][0] = s1[mf * 4 + r];
        red[wid][rl][1] = s2[mf * 4 + r];
      }
  }
  __syncthreads();
  if (tid < 64) {
    float S1 = 0.f, S2 = 0.f;
    #pragma unroll
    for (int w = 0; w < 8; ++w) { S1 += red[w][tid][0]; S2 += red[w][tid][1]; }
    float mean = S1 * (1.0f / 768.0f);
    float var = S2 * (1.0f / 768.0f) - mean * mean;
    rowstat[tid][0] = mean;
    rowstat[tid][1] = rsqrtf(var + 1e-5f);
  }
  __syncthreads();

  float gm[6], bt[6];
  #pragma unroll
  for (int nf = 0; nf < 6; ++nf) {
    gm[nf] = gamma[cbase + nf * 16 + l15];
    bt[nf] = beta[cbase + nf * 16 + l15];
  }
  #pragma unroll
  for (int mf = 0; mf < 4; ++mf) {
    #pragma unroll
    for (int r = 0; r < 4; ++r) {
      const int rl = mf * 16 + g * 4 + r;
      const int m = blk * 64 + rl;
      const int bb = m / 196;
      const int orow = bb * 197 + 1 + (m - bb * 196);
      const float mean = rowstat[rl][0], rstd = rowstat[rl][1];
      float* op = out + (size_t)orow * DTOK + cbase + l15;
      #pragma unroll
      for (int nf = 0; nf < 6; ++nf)
        op[nf * 16] = (acc[mf][nf][r] - mean) * rstd * gm[nf] + bt[nf];
    }
  }
}

extern "C" void kernel_launch(void* const* d_in, const int* in_sizes, int n_in,
                              void* d_out, int out_size, void* d_ws, size_t ws_size,
                              hipStream_t stream) {
  const float* images = (const float*)d_in[0];
  const float* W      = (const float*)d_in[1];
  const float* bias   = (const float*)d_in[2];
  const float* cls    = (const float*)d_in[3];
  const float* gamma  = (const float*)d_in[4];
  const float* beta   = (const float*)d_in[5];
  float* out = (float*)d_out;

  unsigned short* Wb = (unsigned short*)d_ws;                       // 768*768*2 B
  float* bpos = (float*)((char*)d_ws + (size_t)DTOK * DTOK * 2);    // 197*768*4 B

  conv_w<<<(DTOK * DTOK + 255) / 256, 256, 0, stream>>>(W, Wb);
  make_bpos<<<(NTOK * DTOK + 255) / 256, 256, 0, stream>>>(bias, cls, bpos);
  cls_kernel<<<1, 256, 0, stream>>>(bpos, gamma, beta, out);
  vit_main<<<MROWS / 64, 512, 0, stream>>>(images, Wb, bpos, gamma, beta, out);
}